// Round 1
// baseline (139.316 us; speedup 1.0000x reference)
//
#include <hip/hip_runtime.h>
#include <stdint.h>

// SimCLR loss, B=4096, D=512, TAU=0.1.
// out[0] = loss, out[1] = acc(%).
//
// Pipeline:
//   zero_kernel     : zero out[0..1] (harness poisons d_out with 0xAA)
//   prep_kernel     : row L2-normalize both views, store bf16 * sqrt(1/TAU),
//                     fp32 diag[i] = (a_i . b_i)/TAU (the label logit)
//   tiles_kernel    : fused MFMA gram + online softmax partials (m,l) per
//                     (row, col-split) for full_a and full_b
//   finalize_kernel : merge partials + label term -> loss, acc

#define BN 4096
#define DK 512
#define NEG_BIG -1e30f

typedef __attribute__((ext_vector_type(8))) __bf16 bf16x8;
typedef __attribute__((ext_vector_type(4))) float floatx4;

__device__ __forceinline__ unsigned short f2bf(float f) {
  unsigned int u = __float_as_uint(f);
  u += 0x7fffu + ((u >> 16) & 1u);  // round-to-nearest-even
  return (unsigned short)(u >> 16);
}

__global__ void zero_kernel(float* out) {
  if (threadIdx.x < 2) out[threadIdx.x] = 0.0f;
}

// ---------------- prep: normalize rows, bf16 pack, diag label logits -------
__global__ void __launch_bounds__(128) prep_kernel(
    const float* __restrict__ A, const float* __restrict__ Bv,
    unsigned short* __restrict__ An, unsigned short* __restrict__ Bn,
    float* __restrict__ diag) {
  const int row = blockIdx.x;
  const int tid = threadIdx.x;  // 128 threads, 4 floats each = 512
  float4 va = ((const float4*)(A + (size_t)row * DK))[tid];
  float4 vb = ((const float4*)(Bv + (size_t)row * DK))[tid];
  float ssa = va.x * va.x + va.y * va.y + va.z * va.z + va.w * va.w;
  float ssb = vb.x * vb.x + vb.y * vb.y + vb.z * vb.z + vb.w * vb.w;
  float sab = va.x * vb.x + va.y * vb.y + va.z * vb.z + va.w * vb.w;
#pragma unroll
  for (int off = 32; off > 0; off >>= 1) {
    ssa += __shfl_xor(ssa, off);
    ssb += __shfl_xor(ssb, off);
    sab += __shfl_xor(sab, off);
  }
  __shared__ float red[3][2];
  if ((tid & 63) == 0) {
    int w = tid >> 6;
    red[0][w] = ssa; red[1][w] = ssb; red[2][w] = sab;
  }
  __syncthreads();
  ssa = red[0][0] + red[0][1];
  ssb = red[1][0] + red[1][1];
  sab = red[2][0] + red[2][1];
  float na = fmaxf(sqrtf(ssa), 1e-12f);
  float nb = fmaxf(sqrtf(ssb), 1e-12f);
  const float S = 3.16227766016838f;  // sqrt(1/TAU): MFMA dot -> logit directly
  float sa = S / na, sb = S / nb;
  ushort4 pa, pb;
  pa.x = f2bf(va.x * sa); pa.y = f2bf(va.y * sa);
  pa.z = f2bf(va.z * sa); pa.w = f2bf(va.w * sa);
  pb.x = f2bf(vb.x * sb); pb.y = f2bf(vb.y * sb);
  pb.z = f2bf(vb.z * sb); pb.w = f2bf(vb.w * sb);
  ((ushort4*)(An + (size_t)row * DK))[tid] = pa;
  ((ushort4*)(Bn + (size_t)row * DK))[tid] = pb;
  if (tid == 0) diag[row] = (sab / (na * nb)) * 10.0f;  // /TAU
}

// ---------------- tiles: fused gram + online softmax ----------------------
// Unified column space: col c<BN -> A_n row c, c>=BN -> B_n row (c-BN).
//   full_a row i: logits over [B_n cols (=logits_ab), A_n cols (=logits_aa)]
//   full_b row i: logits over [A_n cols (=logits_ba), B_n cols (=logits_bb)]
// Both exclude position (i,i) of BOTH halves: A-half (i,i) is full_a's masked
// diag AND full_b's label; B-half (i,i) is full_a's label AND full_b's masked
// diag. Labels are re-added from fp32 diag[] in finalize.
// grid = (64 row-blocks, 8 col-splits); block = 256 (4 waves x 16 rows).
__global__ void __launch_bounds__(256, 2) tiles_kernel(
    const unsigned short* __restrict__ An, const unsigned short* __restrict__ Bn,
    float* __restrict__ pmA, float* __restrict__ plA,
    float* __restrict__ pmB, float* __restrict__ plB) {
  // 64 cols x 512 bf16 = 64KB. XOR-swizzled in 16B chunks: physical chunk p of
  // col c holds global chunk p ^ (c&7)  -> conflict-balanced ds_read_b128
  // while keeping global_load_lds's lane*16B contiguous LDS placement.
  __shared__ __align__(16) unsigned short tile[64 * DK];

  const int rb = blockIdx.x;     // row block 0..63
  const int split = blockIdx.y;  // col split 0..7 (16 j-tiles each)
  const int tid = threadIdx.x;
  const int lane = tid & 63, w = tid >> 6;
  const int n = lane & 15, q = lane >> 4;
  const int r0 = rb * 64;

  // Persistent A-operand fragments for this wave's 16 rows, both lefts.
  // A layout: lane holds A[m = lane&15][k = q*8 + j], j=0..7, per 32-K chunk.
  bf16x8 afA[16], afB[16];
  {
    const int row = r0 + w * 16 + n;
    const unsigned short* pa = An + (size_t)row * DK + q * 8;
    const unsigned short* pb = Bn + (size_t)row * DK + q * 8;
#pragma unroll
    for (int kc = 0; kc < 16; ++kc) {
      afA[kc] = *(const bf16x8*)(pa + kc * 32);
      afB[kc] = *(const bf16x8*)(pb + kc * 32);
    }
  }

  // Lane-local online softmax state: lane covers cols {cs*16+n}, rows q*4+r.
  float mA[4], lA[4], mB[4], lB[4];
#pragma unroll
  for (int r = 0; r < 4; ++r) { mA[r] = NEG_BIG; lA[r] = 0.f; mB[r] = NEG_BIG; lB[r] = 0.f; }

  for (int t = 0; t < 16; ++t) {
    const int jt = split * 16 + t;
    __syncthreads();
    {  // stage 64 cols; wave w handles cols w*16 .. w*16+15 (1KB each)
      const int cbase = jt * 64;
#pragma unroll
      for (int i = 0; i < 16; ++i) {
        const int cl = w * 16 + i;
        const int c = cbase + cl;
        const unsigned short* src =
            (c < BN) ? (An + (size_t)c * DK) : (Bn + (size_t)(c - BN) * DK);
        const int sw = (lane ^ (cl & 7)) * 8;  // swizzled 16B-chunk source
        __builtin_amdgcn_global_load_lds(
            (const __attribute__((address_space(1))) void*)(src + sw),
            (__attribute__((address_space(3))) void*)(&tile[cl * DK]),
            16, 0, 0);
      }
    }
    __syncthreads();

    floatx4 accA[4], accB[4];
#pragma unroll
    for (int cs = 0; cs < 4; ++cs) {
      floatx4 z = {0.f, 0.f, 0.f, 0.f};
      accA[cs] = z; accB[cs] = z;
    }
    const int nx = n & 7;
#pragma unroll
    for (int kc = 0; kc < 16; ++kc) {
#pragma unroll
      for (int cs = 0; cs < 4; ++cs) {
        const int col = cs * 16 + n;
        const int phys = ((kc * 4 + q) ^ nx) * 8;  // element offset of 16B chunk
        bf16x8 bfr = *(const bf16x8*)(tile + col * DK + phys);
        accA[cs] = __builtin_amdgcn_mfma_f32_16x16x32_bf16(afA[kc], bfr, accA[cs], 0, 0, 0);
        accB[cs] = __builtin_amdgcn_mfma_f32_16x16x32_bf16(afB[kc], bfr, accB[cs], 0, 0, 0);
      }
    }

    // C layout: col = lane&15 (=n), row = q*4 + reg. Special tiles carry the
    // (i,i) positions of each half: exclude for both problems.
    if (jt == rb || jt == rb + 64) {
#pragma unroll
      for (int cs = 0; cs < 4; ++cs)
#pragma unroll
        for (int r = 0; r < 4; ++r) {
          bool kill = (cs == w) && (n == q * 4 + r);
          if (kill) { accA[cs][r] = NEG_BIG; accB[cs][r] = NEG_BIG; }
        }
    }

    // lane-local online update (no cross-lane work per tile)
#pragma unroll
    for (int r = 0; r < 4; ++r) {
      {
        float a0 = accA[0][r], a1 = accA[1][r], a2 = accA[2][r], a3 = accA[3][r];
        float vmax = fmaxf(fmaxf(a0, a1), fmaxf(a2, a3));
        float mn = fmaxf(mA[r], vmax);
        float s = __expf(a0 - mn) + __expf(a1 - mn) + __expf(a2 - mn) + __expf(a3 - mn);
        lA[r] = lA[r] * __expf(mA[r] - mn) + s;
        mA[r] = mn;
      }
      {
        float b0 = accB[0][r], b1 = accB[1][r], b2 = accB[2][r], b3 = accB[3][r];
        float vmax = fmaxf(fmaxf(b0, b1), fmaxf(b2, b3));
        float mn = fmaxf(mB[r], vmax);
        float s = __expf(b0 - mn) + __expf(b1 - mn) + __expf(b2 - mn) + __expf(b3 - mn);
        lB[r] = lB[r] * __expf(mB[r] - mn) + s;
        mB[r] = mn;
      }
    }
  }

  // merge the 16 lanes (same q) covering this row's column subsets
#pragma unroll
  for (int off = 1; off < 16; off <<= 1) {
#pragma unroll
    for (int r = 0; r < 4; ++r) {
      float mo = __shfl_xor(mA[r], off), lo = __shfl_xor(lA[r], off);
      float mn = fmaxf(mA[r], mo);
      lA[r] = lA[r] * __expf(mA[r] - mn) + lo * __expf(mo - mn);
      mA[r] = mn;
      mo = __shfl_xor(mB[r], off); lo = __shfl_xor(lB[r], off);
      mn = fmaxf(mB[r], mo);
      lB[r] = lB[r] * __expf(mB[r] - mn) + lo * __expf(mo - mn);
      mB[r] = mn;
    }
  }
  if (n == 0) {
    const int base = split * BN + r0 + w * 16 + q * 4;
#pragma unroll
    for (int r = 0; r < 4; ++r) {
      pmA[base + r] = mA[r];
      plA[base + r] = lA[r];
      pmB[base + r] = mB[r];
      plB[base + r] = lB[r];
    }
  }
}

// ---------------- finalize: merge splits, add label, reduce ---------------
__global__ void __launch_bounds__(256) finalize_kernel(
    const float* __restrict__ pmA, const float* __restrict__ plA,
    const float* __restrict__ pmB, const float* __restrict__ plB,
    const float* __restrict__ diag, float* __restrict__ out) {
  const int row = blockIdx.x * 256 + threadIdx.x;
  float Ma = NEG_BIG, La = 0.f, Mb = NEG_BIG, Lb = 0.f;
#pragma unroll
  for (int s = 0; s < 8; ++s) {
    float m = pmA[s * BN + row], l = plA[s * BN + row];
    float mn = fmaxf(Ma, m);
    La = La * __expf(Ma - mn) + l * __expf(m - mn);
    Ma = mn;
    m = pmB[s * BN + row]; l = plB[s * BN + row];
    mn = fmaxf(Mb, m);
    Lb = Lb * __expf(Mb - mn) + l * __expf(m - mn);
    Mb = mn;
  }
  const float d = diag[row];
  float corr = (d >= Ma) ? 1.f : 0.f;  // argmax(full_a)==label  <=>  d beats all others
  float mna = fmaxf(Ma, d);
  float lseA = mna + logf(La * __expf(Ma - mna) + __expf(d - mna));
  float mnb = fmaxf(Mb, d);
  float lseB = mnb + logf(Lb * __expf(Mb - mnb) + __expf(d - mnb));
  float lossi = (lseA - d) + (lseB - d);
#pragma unroll
  for (int off = 32; off > 0; off >>= 1) {
    lossi += __shfl_xor(lossi, off);
    corr += __shfl_xor(corr, off);
  }
  __shared__ float sred[2][4];
  if ((threadIdx.x & 63) == 0) {
    int w = threadIdx.x >> 6;
    sred[0][w] = lossi; sred[1][w] = corr;
  }
  __syncthreads();
  if (threadIdx.x == 0) {
    float ls = sred[0][0] + sred[0][1] + sred[0][2] + sred[0][3];
    float cs = sred[1][0] + sred[1][1] + sred[1][2] + sred[1][3];
    atomicAdd(&out[0], ls * (1.0f / 8192.0f));       // mean over 4096 rows, /2
    atomicAdd(&out[1], cs * (100.0f / 4096.0f));     // accuracy %
  }
}

extern "C" void kernel_launch(void* const* d_in, const int* in_sizes, int n_in,
                              void* d_out, int out_size, void* d_ws, size_t ws_size,
                              hipStream_t stream) {
  const float* A = (const float*)d_in[0];
  const float* Bv = (const float*)d_in[1];
  unsigned short* An = (unsigned short*)d_ws;                 // 4096x512 bf16
  unsigned short* Bn = An + (size_t)BN * DK;                  // 4096x512 bf16
  float* diag = (float*)(Bn + (size_t)BN * DK);               // 4096 f32
  float* pmA = diag + BN;                                     // 8x4096 f32 each
  float* plA = pmA + 8 * BN;
  float* pmB = plA + 8 * BN;
  float* plB = pmB + 8 * BN;
  float* out = (float*)d_out;

  zero_kernel<<<1, 64, 0, stream>>>(out);
  prep_kernel<<<BN, 128, 0, stream>>>(A, Bv, An, Bn, diag);
  tiles_kernel<<<dim3(64, 8), 256, 0, stream>>>(An, Bn, pmA, plA, pmB, plB);
  finalize_kernel<<<16, 256, 0, stream>>>(pmA, plA, pmB, plB, diag, out);
}